// Round 6
// baseline (431.127 us; speedup 1.0000x reference)
//
#include <hip/hip_runtime.h>

#define NWG     8
#define NTHR    1024
#define HIDDEN  256
#define HPW     32     // h indices per WG
#define ENC_T   16
#define NTOK    28
#define DECLEN  25

typedef unsigned long long u64;

__device__ __forceinline__ float sigf(float x){ return 1.0f/(1.0f + expf(-x)); }
__device__ __forceinline__ float4 ld4(const float* p){ return *(const float4*)p; }

__device__ __forceinline__ void astore(u64* p, u64 v){
  __hip_atomic_store(p, v, __ATOMIC_RELAXED, __HIP_MEMORY_SCOPE_AGENT);
}
__device__ __forceinline__ u64 aload(const u64* p){
  return __hip_atomic_load(p, __ATOMIC_RELAXED, __HIP_MEMORY_SCOPE_AGENT);
}

__global__ __launch_bounds__(NTHR, 1) void vae_lstm_kernel(
    const int* __restrict__ data, const int* __restrict__ data_c, const int* __restrict__ target_c,
    const float* __restrict__ cond_emb, const float* __restrict__ enc_emb,
    const float* __restrict__ eWih, const float* __restrict__ eWhh,
    const float* __restrict__ ebih, const float* __restrict__ ebhh,
    const float* __restrict__ hmuW, const float* __restrict__ hmub,
    const float* __restrict__ cmuW, const float* __restrict__ cmub,
    const float* __restrict__ fc1W, const float* __restrict__ fc1b,
    const float* __restrict__ fc2W, const float* __restrict__ fc2b,
    const float* __restrict__ dec_emb, const float* __restrict__ dWih,
    const float* __restrict__ dWhh, const float* __restrict__ dbih, const float* __restrict__ dbhh,
    const float* __restrict__ outW, const float* __restrict__ outb,
    float* __restrict__ out, u64* __restrict__ hb, u64* __restrict__ cb)
{
  __shared__ __align__(16) float h_sh[HIDDEN];
  __shared__ __align__(16) float c2_sh[HIDDEN];
  __shared__ float pxe_sh[ENC_T][128];
  __shared__ float pxd_sh[NTOK][128];
  __shared__ float g_sh[128];
  __shared__ float mu_sh[64];
  __shared__ float l_sh[NTOK];
  __shared__ float c_sh[HPW];
  __shared__ float tc_sh[8];
  __shared__ float outb_sh[NTOK];
  __shared__ int tok_sh;

  const int w   = blockIdx.x;
  const int tid = threadIdx.x;
  const int r   = tid >> 3;        // 0..127 : gate*32 + j
  const int p   = tid & 7;         // column part (32 cols each) -- R1/R4-identical tree
  const int gate = r >> 5;         // 0..3 (i,f,g,o)
  const int j    = r & 31;         // h index within WG
  const int grow = gate*HIDDEN + w*HPW + j;   // global gate row 0..1023

  // ---------------- prologue: weights -> registers (R4-identical per row) ----------------
  float4 wenc[8], wdec[8], wout[8];
  #pragma unroll
  for (int k=0;k<8;++k){
    const int c = (p*8+k)*4;
    wenc[k] = ld4(eWhh + (size_t)grow*HIDDEN + c);
    wdec[k] = ld4(dWhh + (size_t)grow*HIDDEN + c);
  }
  if (r < NTOK){
    #pragma unroll
    for (int k=0;k<8;++k) wout[k] = ld4(outW + (size_t)r*HIDDEN + (p*8+k)*4);
  } else {
    #pragma unroll
    for (int k=0;k<8;++k) wout[k] = make_float4(0.f,0.f,0.f,0.f);
  }

  // px for encoder steps: x_t @ Wih.T + bih + bhh (R4-identical serial order per row)
  {
    const float bsum = ebih[grow] + ebhh[grow];
    for (int ss = p; ss < ENC_T; ss += 8){
      const float* x  = enc_emb + (size_t)data[ss]*HIDDEN;
      const float* Wr = eWih + (size_t)grow*HIDDEN;
      float a = bsum;
      for (int c4=0;c4<64;++c4){
        float4 wv = ld4(Wr + c4*4); float4 xv = ld4(x + c4*4);
        a = fmaf(wv.x,xv.x, fmaf(wv.y,xv.y, fmaf(wv.z,xv.z, fmaf(wv.w,xv.w, a))));
      }
      pxe_sh[ss][r] = a;
    }
  }
  // px for ALL 28 possible decoder tokens (R4-identical per row)
  {
    const float bsum = dbih[grow] + dbhh[grow];
    for (int tk = p; tk < NTOK; tk += 8){
      const float* x  = dec_emb + (size_t)tk*HIDDEN;
      const float* Wr = dWih + (size_t)grow*HIDDEN;
      float a = bsum;
      for (int c4=0;c4<64;++c4){
        float4 wv = ld4(Wr + c4*4); float4 xv = ld4(x + c4*4);
        a = fmaf(wv.x,fmaxf(xv.x,0.f), fmaf(wv.y,fmaxf(xv.y,0.f),
            fmaf(wv.z,fmaxf(xv.z,0.f), fmaf(wv.w,fmaxf(xv.w,0.f), a))));
      }
      pxd_sh[tk][r] = a;
    }
  }

  const int dcnd = data_c[0];
  if (tid < 8)    tc_sh[tid]   = cond_emb[target_c[0]*8 + tid];
  if (tid < NTOK) outb_sh[tid] = outb[tid];
  if (tid < HIDDEN)
    h_sh[tid] = (tid >= HIDDEN-8) ? cond_emb[dcnd*8 + (tid-(HIDDEN-8))] : 0.f;
  if (tid < HPW){
    int idx = w*HPW + tid;
    c_sh[tid] = (idx >= HIDDEN-8) ? cond_emb[dcnd*8 + (idx-(HIDDEN-8))] : 0.f;
  }
  __syncthreads();

  int step = 1;
  // ---------------- encoder: 16 sequential steps ----------------
  for (int es=0; es<ENC_T; ++es, ++step){
    const float4* h4 = (const float4*)h_sh;
    float a = 0.f;
    #pragma unroll
    for (int k=0;k<8;++k){
      float4 hv = h4[p*8+k]; float4 wv = wenc[k];
      a = fmaf(wv.x,hv.x, fmaf(wv.y,hv.y, fmaf(wv.z,hv.z, fmaf(wv.w,hv.w, a))));
    }
    a += __shfl_xor(a,1); a += __shfl_xor(a,2); a += __shfl_xor(a,4);
    if (p==0) g_sh[r] = a + pxe_sh[es][r];
    __syncthreads();
    if (tid < HPW){
      float gi=g_sh[tid], gf=g_sh[32+tid], gg=g_sh[64+tid], go=g_sh[96+tid];
      float cc = sigf(gf)*c_sh[tid] + sigf(gi)*tanhf(gg);
      float hh = sigf(go)*tanhf(cc);
      c_sh[tid]=cc;
      astore(&hb[(step&1)*HIDDEN + w*HPW + tid], ((u64)step<<32) | (u64)__float_as_uint(hh));
      if (es==ENC_T-1)
        astore(&cb[w*HPW + tid], ((u64)step<<32) | (u64)__float_as_uint(cc));
    }
    // tag-in-payload: threads 0..255 poll their own slot (R4-identical protocol)
    if (tid < HIDDEN){
      u64 v;
      const u64* slot = hb + (step&1)*HIDDEN + tid;
      do { v = aload(slot); } while ((unsigned)(v>>32) != (unsigned)step);
      h_sh[tid] = __uint_as_float((unsigned)v);
    }
    __syncthreads();
  }

  // ---------------- mid: mu's + fc1/fc2 (redundant per WG, R4-identical) ----------------
  if (tid < HIDDEN){
    u64 v;
    do { v = aload(&cb[tid]); } while ((unsigned)(v>>32) != (unsigned)ENC_T);
    c2_sh[tid] = __uint_as_float((unsigned)v);
  }
  __syncthreads();
  if (tid < 256){
    int row = tid>>2, q = tid&3;   // 64 rows (32 h_mu + 32 c_mu), 4 threads each
    const float* Wr = (row<32) ? (hmuW + (size_t)row*HIDDEN) : (cmuW + (size_t)(row-32)*HIDDEN);
    const float* v  = (row<32) ? h_sh : c2_sh;
    float a=0.f;
    for (int c4=q*16; c4<q*16+16; ++c4){
      float4 wv = ld4(Wr + c4*4);
      float4 vv = *(const float4*)(v + c4*4);
      a = fmaf(wv.x,vv.x, fmaf(wv.y,vv.y, fmaf(wv.z,vv.z, fmaf(wv.w,vv.w, a))));
    }
    a += __shfl_xor(a,1); a += __shfl_xor(a,2);
    if (q==0) mu_sh[row] = a + ((row<32)? hmub[row] : cmub[row-32]);
  }
  __syncthreads();
  {
    float a = 0.f;
    if (tid < 256){
      a = fc1b[tid];
      const float* Wr = fc1W + (size_t)tid*40;
      #pragma unroll
      for (int k=0;k<32;++k) a = fmaf(Wr[k], mu_sh[k], a);
      #pragma unroll
      for (int k=0;k<8;++k)  a = fmaf(Wr[32+k], tc_sh[k], a);
    }
    float a2 = 0.f;
    if (tid < HPW){
      int idx = w*HPW + tid;
      a2 = fc2b[idx];
      const float* W2 = fc2W + (size_t)idx*40;
      #pragma unroll
      for (int k=0;k<32;++k) a2 = fmaf(W2[k], mu_sh[32+k], a2);
      #pragma unroll
      for (int k=0;k<8;++k)  a2 = fmaf(W2[32+k], tc_sh[k], a2);
    }
    __syncthreads();
    if (tid < 256) h_sh[tid] = a;   // decoder h0 (redundant in every WG)
    if (tid < HPW) c_sh[tid] = a2;  // decoder c0 (own slice only)
    __syncthreads();
  }

  // ---------------- decoder: 25 sequential steps ----------------
  int tok = 0; // SOS
  for (int dt=0; dt<DECLEN; ++dt, ++step){
    const float4* h4 = (const float4*)h_sh;
    float a=0.f;
    #pragma unroll
    for (int k=0;k<8;++k){
      float4 hv = h4[p*8+k]; float4 wv = wdec[k];
      a = fmaf(wv.x,hv.x, fmaf(wv.y,hv.y, fmaf(wv.z,hv.z, fmaf(wv.w,hv.w, a))));
    }
    a += __shfl_xor(a,1); a += __shfl_xor(a,2); a += __shfl_xor(a,4);
    if (p==0) g_sh[r] = a + pxd_sh[tok][r];
    __syncthreads();
    if (tid < HPW){
      float gi=g_sh[tid], gf=g_sh[32+tid], gg=g_sh[64+tid], go=g_sh[96+tid];
      float cc = sigf(gf)*c_sh[tid] + sigf(gi)*tanhf(gg);
      float hh = sigf(go)*tanhf(cc);
      c_sh[tid]=cc;
      astore(&hb[(step&1)*HIDDEN + w*HPW + tid], ((u64)step<<32) | (u64)__float_as_uint(hh));
    }
    if (tid < HIDDEN){
      u64 v;
      const u64* slot = hb + (step&1)*HIDDEN + tid;
      do { v = aload(slot); } while ((unsigned)(v>>32) != (unsigned)step);
      h_sh[tid] = __uint_as_float((unsigned)v);
    }
    __syncthreads();
    // logits + argmax, redundant in every WG (R4-identical order)
    {
      const float4* h4b = (const float4*)h_sh;
      if (r < NTOK){
        float la=0.f;
        #pragma unroll
        for (int k=0;k<8;++k){
          float4 hv = h4b[p*8+k]; float4 wv = wout[k];
          la = fmaf(wv.x,hv.x, fmaf(wv.y,hv.y, fmaf(wv.z,hv.z, fmaf(wv.w,hv.w, la))));
        }
        la += __shfl_xor(la,1); la += __shfl_xor(la,2); la += __shfl_xor(la,4);
        if (p==0) l_sh[r] = la + outb_sh[r];
      }
    }
    __syncthreads();
    if (tid==0){
      float best = l_sh[0]; int bi=0;
      #pragma unroll
      for (int i=1;i<NTOK;++i){ if (l_sh[i] > best){ best=l_sh[i]; bi=i; } }
      tok_sh = bi;
    }
    __syncthreads();
    tok = tok_sh;
    if (w==0){
      if (tid < NTOK) out[dt*NTOK + tid] = l_sh[tid];
      if (tid==0)     out[DECLEN*NTOK + dt] = (float)tok_sh;
    }
  }
}

extern "C" void kernel_launch(void* const* d_in, const int* in_sizes, int n_in,
                              void* d_out, int out_size, void* d_ws, size_t ws_size,
                              hipStream_t stream)
{
  u64* hb = (u64*)d_ws;                        // double-buffered tagged h: 2*256 u64 (4 KB)
  u64* cb = (u64*)((char*)d_ws + 4096);        // tagged cT: 256 u64 (2 KB)
  hipMemsetAsync(d_ws, 0, 6144, stream);       // clear tags every launch

  vae_lstm_kernel<<<NWG, NTHR, 0, stream>>>(
    (const int*)d_in[0], (const int*)d_in[1], (const int*)d_in[2],
    (const float*)d_in[3], (const float*)d_in[4],
    (const float*)d_in[5], (const float*)d_in[6], (const float*)d_in[7], (const float*)d_in[8],
    (const float*)d_in[9], (const float*)d_in[10], (const float*)d_in[11], (const float*)d_in[12],
    (const float*)d_in[13], (const float*)d_in[14], (const float*)d_in[15], (const float*)d_in[16],
    (const float*)d_in[17], (const float*)d_in[18], (const float*)d_in[19], (const float*)d_in[20],
    (const float*)d_in[21], (const float*)d_in[22], (const float*)d_in[23],
    (float*)d_out, hb, cb);
}

// Round 8
// 413.423 us; speedup vs baseline: 1.0428x; 1.0428x over previous
//
#include <hip/hip_runtime.h>

#define NWG     8
#define NTHR    256
#define HIDDEN  256
#define HPW     32     // h indices per WG
#define ENC_T   16
#define NTOK    28
#define DECLEN  25

typedef unsigned long long u64;

__device__ __forceinline__ float sigf(float x){ return 1.0f/(1.0f + expf(-x)); }
__device__ __forceinline__ float4 ld4(const float* p){ return *(const float4*)p; }

__device__ __forceinline__ void astore(u64* p, u64 v){
  __hip_atomic_store(p, v, __ATOMIC_RELAXED, __HIP_MEMORY_SCOPE_AGENT);
}
__device__ __forceinline__ u64 aload(const u64* p){
  return __hip_atomic_load(p, __ATOMIC_RELAXED, __HIP_MEMORY_SCOPE_AGENT);
}

__global__ __launch_bounds__(NTHR, 1) void vae_lstm_kernel(
    const int* __restrict__ data, const int* __restrict__ data_c, const int* __restrict__ target_c,
    const float* __restrict__ cond_emb, const float* __restrict__ enc_emb,
    const float* __restrict__ eWih, const float* __restrict__ eWhh,
    const float* __restrict__ ebih, const float* __restrict__ ebhh,
    const float* __restrict__ hmuW, const float* __restrict__ hmub,
    const float* __restrict__ cmuW, const float* __restrict__ cmub,
    const float* __restrict__ fc1W, const float* __restrict__ fc1b,
    const float* __restrict__ fc2W, const float* __restrict__ fc2b,
    const float* __restrict__ dec_emb, const float* __restrict__ dWih,
    const float* __restrict__ dWhh, const float* __restrict__ dbih, const float* __restrict__ dbhh,
    const float* __restrict__ outW, const float* __restrict__ outb,
    float* __restrict__ out, u64* __restrict__ hb, u64* __restrict__ cb)
{
  __shared__ __align__(16) float h_sh[HIDDEN];
  __shared__ __align__(16) float c2_sh[HIDDEN];
  __shared__ float pxe_sh[ENC_T][128];
  __shared__ float pxd_sh[NTOK][128];
  __shared__ float g_sh[128];
  __shared__ float mu_sh[64];
  __shared__ float l_sh[NTOK];
  __shared__ float c_sh[HPW];
  __shared__ float tc_sh[8];
  __shared__ float outb_sh[NTOK];
  __shared__ int tok_sh;

  const int w   = blockIdx.x;
  const int tid = threadIdx.x;
  const int r   = tid >> 3;        // 0..31
  const int p   = tid & 7;         // 32-col chunk (R4-identical per-row split)
  const int gate = r >> 3;         // 0..3 (i,f,g,o)
  const int j8   = r & 7;          // base h offset; this thread owns j = j8+8q, q=0..3

  // ---------------- prologue: weights -> registers (R4-identical per row) ----------------
  float4 wenc[4][8], wdec[4][8], wout[8];
  #pragma unroll
  for (int q=0;q<4;++q){
    const int grow = gate*HIDDEN + w*HPW + j8 + 8*q;
    #pragma unroll
    for (int k=0;k<8;++k){
      const int c = (p*8+k)*4;
      wenc[q][k] = ld4(eWhh + (size_t)grow*HIDDEN + c);
      wdec[q][k] = ld4(dWhh + (size_t)grow*HIDDEN + c);
    }
  }
  if (r < NTOK){
    #pragma unroll
    for (int k=0;k<8;++k) wout[k] = ld4(outW + (size_t)r*HIDDEN + (p*8+k)*4);
  } else {
    #pragma unroll
    for (int k=0;k<8;++k) wout[k] = make_float4(0.f,0.f,0.f,0.f);
  }

  // px encoder: 4 rows/thread, steps split over p (R4-identical chain per row)
  #pragma unroll
  for (int q=0;q<4;++q){
    const int row  = gate*32 + j8 + 8*q;             // 0..127 within-WG row id
    const int grow = gate*HIDDEN + w*HPW + j8 + 8*q;
    const float bsum = ebih[grow] + ebhh[grow];
    for (int ss = p; ss < ENC_T; ss += 8){
      const float* x  = enc_emb + (size_t)data[ss]*HIDDEN;
      const float* Wr = eWih + (size_t)grow*HIDDEN;
      float a = bsum;
      for (int c4=0;c4<64;++c4){
        float4 wv = ld4(Wr + c4*4); float4 xv = ld4(x + c4*4);
        a = fmaf(wv.x,xv.x, fmaf(wv.y,xv.y, fmaf(wv.z,xv.z, fmaf(wv.w,xv.w, a))));
      }
      pxe_sh[ss][row] = a;
    }
  }
  // px decoder, all 28 tokens (R4-identical chain per row)
  #pragma unroll
  for (int q=0;q<4;++q){
    const int row  = gate*32 + j8 + 8*q;
    const int grow = gate*HIDDEN + w*HPW + j8 + 8*q;
    const float bsum = dbih[grow] + dbhh[grow];
    for (int tk = p; tk < NTOK; tk += 8){
      const float* x  = dec_emb + (size_t)tk*HIDDEN;
      const float* Wr = dWih + (size_t)grow*HIDDEN;
      float a = bsum;
      for (int c4=0;c4<64;++c4){
        float4 wv = ld4(Wr + c4*4); float4 xv = ld4(x + c4*4);
        a = fmaf(wv.x,fmaxf(xv.x,0.f), fmaf(wv.y,fmaxf(xv.y,0.f),
            fmaf(wv.z,fmaxf(xv.z,0.f), fmaf(wv.w,fmaxf(xv.w,0.f), a))));
      }
      pxd_sh[tk][row] = a;
    }
  }

  const int dcnd = data_c[0];
  if (tid < 8)    tc_sh[tid]   = cond_emb[target_c[0]*8 + tid];
  if (tid < NTOK) outb_sh[tid] = outb[tid];
  h_sh[tid] = (tid >= HIDDEN-8) ? cond_emb[dcnd*8 + (tid-(HIDDEN-8))] : 0.f;
  if (tid < HPW){
    int idx = w*HPW + tid;
    c_sh[tid] = (idx >= HIDDEN-8) ? cond_emb[dcnd*8 + (idx-(HIDDEN-8))] : 0.f;
  }
  __syncthreads();

  int step = 1;
  // ---------------- encoder: 16 sequential steps ----------------
  for (int es=0; es<ENC_T; ++es, ++step){
    const float4* h4 = (const float4*)h_sh;
    float a0=0.f, a1=0.f, a2=0.f, a3=0.f;
    #pragma unroll
    for (int k=0;k<8;++k){
      float4 hv = h4[p*8+k];
      float4 w0=wenc[0][k], w1=wenc[1][k], w2=wenc[2][k], w3=wenc[3][k];
      a0 = fmaf(w0.x,hv.x, fmaf(w0.y,hv.y, fmaf(w0.z,hv.z, fmaf(w0.w,hv.w, a0))));
      a1 = fmaf(w1.x,hv.x, fmaf(w1.y,hv.y, fmaf(w1.z,hv.z, fmaf(w1.w,hv.w, a1))));
      a2 = fmaf(w2.x,hv.x, fmaf(w2.y,hv.y, fmaf(w2.z,hv.z, fmaf(w2.w,hv.w, a2))));
      a3 = fmaf(w3.x,hv.x, fmaf(w3.y,hv.y, fmaf(w3.z,hv.z, fmaf(w3.w,hv.w, a3))));
    }
    a0 += __shfl_xor(a0,1); a0 += __shfl_xor(a0,2); a0 += __shfl_xor(a0,4);
    a1 += __shfl_xor(a1,1); a1 += __shfl_xor(a1,2); a1 += __shfl_xor(a1,4);
    a2 += __shfl_xor(a2,1); a2 += __shfl_xor(a2,2); a2 += __shfl_xor(a2,4);
    a3 += __shfl_xor(a3,1); a3 += __shfl_xor(a3,2); a3 += __shfl_xor(a3,4);
    if (p==0){
      const int row = gate*32 + j8;
      g_sh[row]      = a0 + pxe_sh[es][row];
      g_sh[row + 8]  = a1 + pxe_sh[es][row + 8];
      g_sh[row + 16] = a2 + pxe_sh[es][row + 16];
      g_sh[row + 24] = a3 + pxe_sh[es][row + 24];
    }
    __syncthreads();
    if (tid < HPW){
      float gi=g_sh[tid], gf=g_sh[32+tid], gg=g_sh[64+tid], go=g_sh[96+tid];
      float cc = sigf(gf)*c_sh[tid] + sigf(gi)*tanhf(gg);
      float hh = sigf(go)*tanhf(cc);
      c_sh[tid]=cc;
      astore(&hb[(step&1)*HIDDEN + w*HPW + tid], ((u64)(unsigned)step<<32) | (u64)__float_as_uint(hh));
      if (es==ENC_T-1)
        astore(&cb[w*HPW + tid], ((u64)(unsigned)step<<32) | (u64)__float_as_uint(cc));
    }
    // tag-in-payload poll: each thread its own slot (R4-identical protocol, parity dbuf)
    {
      u64 v;
      const u64* slot = hb + (step&1)*HIDDEN + tid;
      do { v = aload(slot); } while ((unsigned)(v>>32) != (unsigned)step);
      h_sh[tid] = __uint_as_float((unsigned)v);
    }
    __syncthreads();
  }

  // ---------------- mid: mu's + fc1/fc2 (redundant per WG, R4-identical) ----------------
  {
    u64 v;
    do { v = aload(&cb[tid]); } while ((unsigned)(v>>32) != (unsigned)ENC_T);
    c2_sh[tid] = __uint_as_float((unsigned)v);
  }
  __syncthreads();
  {
    int row = tid>>2, q = tid&3;   // 64 rows (32 h_mu + 32 c_mu), 4 threads each
    const float* Wr = (row<32) ? (hmuW + (size_t)row*HIDDEN) : (cmuW + (size_t)(row-32)*HIDDEN);
    const float* v  = (row<32) ? h_sh : c2_sh;
    float a=0.f;
    for (int c4=q*16; c4<q*16+16; ++c4){
      float4 wv = ld4(Wr + c4*4);
      float4 vv = *(const float4*)(v + c4*4);
      a = fmaf(wv.x,vv.x, fmaf(wv.y,vv.y, fmaf(wv.z,vv.z, fmaf(wv.w,vv.w, a))));
    }
    a += __shfl_xor(a,1); a += __shfl_xor(a,2);
    if (q==0) mu_sh[row] = a + ((row<32)? hmub[row] : cmub[row-32]);
  }
  __syncthreads();
  {
    float a = fc1b[tid];
    const float* Wr = fc1W + (size_t)tid*40;
    #pragma unroll
    for (int k=0;k<32;++k) a = fmaf(Wr[k], mu_sh[k], a);
    #pragma unroll
    for (int k=0;k<8;++k)  a = fmaf(Wr[32+k], tc_sh[k], a);
    float a2 = 0.f;
    if (tid < HPW){
      int idx = w*HPW + tid;
      a2 = fc2b[idx];
      const float* W2 = fc2W + (size_t)idx*40;
      #pragma unroll
      for (int k=0;k<32;++k) a2 = fmaf(W2[k], mu_sh[32+k], a2);
      #pragma unroll
      for (int k=0;k<8;++k)  a2 = fmaf(W2[32+k], tc_sh[k], a2);
    }
    __syncthreads();
    h_sh[tid] = a;                 // decoder h0 (full, redundant in every WG)
    if (tid < HPW) c_sh[tid] = a2; // decoder c0 (own slice only)
    __syncthreads();
  }

  // ---------------- decoder: 25 sequential steps ----------------
  int tok = 0; // SOS
  for (int dt=0; dt<DECLEN; ++dt, ++step){
    const float4* h4 = (const float4*)h_sh;
    float a0=0.f, a1=0.f, a2=0.f, a3=0.f;
    #pragma unroll
    for (int k=0;k<8;++k){
      float4 hv = h4[p*8+k];
      float4 w0=wdec[0][k], w1=wdec[1][k], w2=wdec[2][k], w3=wdec[3][k];
      a0 = fmaf(w0.x,hv.x, fmaf(w0.y,hv.y, fmaf(w0.z,hv.z, fmaf(w0.w,hv.w, a0))));
      a1 = fmaf(w1.x,hv.x, fmaf(w1.y,hv.y, fmaf(w1.z,hv.z, fmaf(w1.w,hv.w, a1))));
      a2 = fmaf(w2.x,hv.x, fmaf(w2.y,hv.y, fmaf(w2.z,hv.z, fmaf(w2.w,hv.w, a2))));
      a3 = fmaf(w3.x,hv.x, fmaf(w3.y,hv.y, fmaf(w3.z,hv.z, fmaf(w3.w,hv.w, a3))));
    }
    a0 += __shfl_xor(a0,1); a0 += __shfl_xor(a0,2); a0 += __shfl_xor(a0,4);
    a1 += __shfl_xor(a1,1); a1 += __shfl_xor(a1,2); a1 += __shfl_xor(a1,4);
    a2 += __shfl_xor(a2,1); a2 += __shfl_xor(a2,2); a2 += __shfl_xor(a2,4);
    a3 += __shfl_xor(a3,1); a3 += __shfl_xor(a3,2); a3 += __shfl_xor(a3,4);
    if (p==0){
      const int row = gate*32 + j8;
      g_sh[row]      = a0 + pxd_sh[tok][row];
      g_sh[row + 8]  = a1 + pxd_sh[tok][row + 8];
      g_sh[row + 16] = a2 + pxd_sh[tok][row + 16];
      g_sh[row + 24] = a3 + pxd_sh[tok][row + 24];
    }
    __syncthreads();
    if (tid < HPW){
      float gi=g_sh[tid], gf=g_sh[32+tid], gg=g_sh[64+tid], go=g_sh[96+tid];
      float cc = sigf(gf)*c_sh[tid] + sigf(gi)*tanhf(gg);
      float hh = sigf(go)*tanhf(cc);
      c_sh[tid]=cc;
      astore(&hb[(step&1)*HIDDEN + w*HPW + tid], ((u64)(unsigned)step<<32) | (u64)__float_as_uint(hh));
    }
    {
      u64 v;
      const u64* slot = hb + (step&1)*HIDDEN + tid;
      do { v = aload(slot); } while ((unsigned)(v>>32) != (unsigned)step);
      h_sh[tid] = __uint_as_float((unsigned)v);
    }
    __syncthreads();
    // logits from NEW h + argmax, redundant in every WG (R4-identical order)
    {
      const float4* h4b = (const float4*)h_sh;
      if (r < NTOK){
        float la=0.f;
        #pragma unroll
        for (int k=0;k<8;++k){
          float4 hv = h4b[p*8+k]; float4 wv = wout[k];
          la = fmaf(wv.x,hv.x, fmaf(wv.y,hv.y, fmaf(wv.z,hv.z, fmaf(wv.w,hv.w, la))));
        }
        la += __shfl_xor(la,1); la += __shfl_xor(la,2); la += __shfl_xor(la,4);
        if (p==0) l_sh[r] = la + outb_sh[r];
      }
    }
    __syncthreads();
    if (tid==0){
      float best = l_sh[0]; int bi=0;
      #pragma unroll
      for (int i=1;i<NTOK;++i){ if (l_sh[i] > best){ best=l_sh[i]; bi=i; } }
      tok_sh = bi;
    }
    __syncthreads();
    tok = tok_sh;
    if (w==0){
      if (tid < NTOK) out[dt*NTOK + tid] = l_sh[tid];
      if (tid==0)     out[DECLEN*NTOK + dt] = (float)tok_sh;
    }
  }
}

extern "C" void kernel_launch(void* const* d_in, const int* in_sizes, int n_in,
                              void* d_out, int out_size, void* d_ws, size_t ws_size,
                              hipStream_t stream)
{
  u64* hb = (u64*)d_ws;                        // parity double-buffered tagged h: 2*256 u64 (4 KB)
  u64* cb = (u64*)((char*)d_ws + 4096);        // tagged cT: 256 u64 (2 KB)
  hipMemsetAsync(d_ws, 0, 6144, stream);       // clear tags every launch

  vae_lstm_kernel<<<NWG, NTHR, 0, stream>>>(
    (const int*)d_in[0], (const int*)d_in[1], (const int*)d_in[2],
    (const float*)d_in[3], (const float*)d_in[4],
    (const float*)d_in[5], (const float*)d_in[6], (const float*)d_in[7], (const float*)d_in[8],
    (const float*)d_in[9], (const float*)d_in[10], (const float*)d_in[11], (const float*)d_in[12],
    (const float*)d_in[13], (const float*)d_in[14], (const float*)d_in[15], (const float*)d_in[16],
    (const float*)d_in[17], (const float*)d_in[18], (const float*)d_in[19], (const float*)d_in[20],
    (const float*)d_in[21], (const float*)d_in[22], (const float*)d_in[23],
    (float*)d_out, hb, cb);
}

// Round 10
// 280.311 us; speedup vs baseline: 1.5380x; 1.4749x over previous
//
#include <hip/hip_runtime.h>

#define NTHR    256
#define HIDDEN  256
#define HPW     8      // h indices per WG
#define ENC_T   16
#define NTOK    28
#define DECLEN  25
#define REPSTRIDE 2048 // u64s per replica region (16 KB)

typedef unsigned long long u64;

__device__ __forceinline__ float sigf(float x){ return 1.0f/(1.0f + expf(-x)); }
__device__ __forceinline__ float4 ld4(const float* p){ return *(const float4*)p; }

// Agent-scope (IC) path — proven protocol from R4/R8.
__device__ __forceinline__ void astore(u64* p, u64 v){
  __hip_atomic_store(p, v, __ATOMIC_RELAXED, __HIP_MEMORY_SCOPE_AGENT);
}
__device__ __forceinline__ u64 aload(const u64* p){
  return __hip_atomic_load(p, __ATOMIC_RELAXED, __HIP_MEMORY_SCOPE_AGENT);
}
// L2-scope fast path: sc0 = L1-bypass, coherent at the XCD-shared L2.
__device__ __forceinline__ void st_sc0(u64* p, u64 v){
  asm volatile("global_store_dwordx2 %0, %1, off sc0\n\ts_waitcnt vmcnt(0)"
               :: "v"(p), "v"(v) : "memory");
}
__device__ __forceinline__ u64 ld_sc0(const u64* p){
  u64 r;
  asm volatile("global_load_dwordx2 %0, %1, off sc0\n\ts_waitcnt vmcnt(0)"
               : "=v"(r) : "v"(p) : "memory");
  return r;
}
// Spin until either copy carries the wanted tag; IC copy guarantees progress.
__device__ __forceinline__ float poll_dual(const u64* l2s, const u64* ics, unsigned want){
  u64 v; int it = 0;
  for(;;){
    v = ld_sc0(l2s);
    if ((unsigned)(v>>32) == want) break;
    if ((it++ & 3) == 3){
      v = aload(ics);
      if ((unsigned)(v>>32) == want) break;
    }
  }
  return __uint_as_float((unsigned)v);
}

__global__ __launch_bounds__(NTHR, 1) void vae_lstm_kernel(
    const int* __restrict__ data, const int* __restrict__ data_c, const int* __restrict__ target_c,
    const float* __restrict__ cond_emb, const float* __restrict__ enc_emb,
    const float* __restrict__ eWih, const float* __restrict__ eWhh,
    const float* __restrict__ ebih, const float* __restrict__ ebhh,
    const float* __restrict__ hmuW, const float* __restrict__ hmub,
    const float* __restrict__ cmuW, const float* __restrict__ cmub,
    const float* __restrict__ fc1W, const float* __restrict__ fc1b,
    const float* __restrict__ fc2W, const float* __restrict__ fc2b,
    const float* __restrict__ dec_emb, const float* __restrict__ dWih,
    const float* __restrict__ dWhh, const float* __restrict__ dbih, const float* __restrict__ dbhh,
    const float* __restrict__ outW, const float* __restrict__ outb,
    float* __restrict__ out, u64* __restrict__ ws, int nrep)
{
  __shared__ __align__(16) float h_sh[HIDDEN];
  __shared__ __align__(16) float c2_sh[HIDDEN];
  __shared__ float pxe_sh[ENC_T][32];
  __shared__ float pxd_sh[NTOK][32];
  __shared__ float g_sh[32];
  __shared__ float mu_sh[64];
  __shared__ float l_sh[NTOK];
  __shared__ float c_sh[HPW];
  __shared__ float tc_sh[8];
  __shared__ float outb_sh[NTOK];
  __shared__ int tok_sh;

  const int rep = blockIdx.x % nrep;   // replica (hoped: one replica per XCD)
  const int w   = blockIdx.x / nrep;   // worker 0..31 within replica
  const int tid = threadIdx.x;

  u64* base = ws + (size_t)rep * REPSTRIDE;
  u64* hbL2 = base;          // 2 parities x 256
  u64* hbIC = base + 512;    // 2 parities x 256
  u64* cbL2 = base + 1024;   // 256
  u64* cbIC = base + 1280;   // 256

  const int r   = tid >> 3;        // 0..31 : gate*8 + j   (R4-identical)
  const int p   = tid & 7;         // column part (32 cols each)
  const int gate = r >> 3;         // 0..3 (i,f,g,o)
  const int j    = r & 7;          // h index within WG
  const int grow = gate*HIDDEN + w*HPW + j;   // global gate row 0..1023

  // ---------------- prologue: weights -> registers (R4-identical) ----------------
  float4 wenc[8], wdec[8], wout[8];
  #pragma unroll
  for (int k=0;k<8;++k){
    const int c = (p*8+k)*4;
    wenc[k] = ld4(eWhh + (size_t)grow*HIDDEN + c);
    wdec[k] = ld4(dWhh + (size_t)grow*HIDDEN + c);
  }
  if (r < NTOK){
    #pragma unroll
    for (int k=0;k<8;++k) wout[k] = ld4(outW + (size_t)r*HIDDEN + (p*8+k)*4);
  } else {
    #pragma unroll
    for (int k=0;k<8;++k) wout[k] = make_float4(0.f,0.f,0.f,0.f);
  }

  // px for encoder steps (R4-identical order)
  {
    const float bsum = ebih[grow] + ebhh[grow];
    for (int ss = p; ss < ENC_T; ss += 8){
      const float* x  = enc_emb + (size_t)data[ss]*HIDDEN;
      const float* Wr = eWih + (size_t)grow*HIDDEN;
      float a = bsum;
      for (int c4=0;c4<64;++c4){
        float4 wv = ld4(Wr + c4*4); float4 xv = ld4(x + c4*4);
        a = fmaf(wv.x,xv.x, fmaf(wv.y,xv.y, fmaf(wv.z,xv.z, fmaf(wv.w,xv.w, a))));
      }
      pxe_sh[ss][r] = a;
    }
  }
  // px for ALL 28 decoder tokens (R4-identical order)
  {
    const float bsum = dbih[grow] + dbhh[grow];
    for (int tk = p; tk < NTOK; tk += 8){
      const float* x  = dec_emb + (size_t)tk*HIDDEN;
      const float* Wr = dWih + (size_t)grow*HIDDEN;
      float a = bsum;
      for (int c4=0;c4<64;++c4){
        float4 wv = ld4(Wr + c4*4); float4 xv = ld4(x + c4*4);
        a = fmaf(wv.x,fmaxf(xv.x,0.f), fmaf(wv.y,fmaxf(xv.y,0.f),
            fmaf(wv.z,fmaxf(xv.z,0.f), fmaf(wv.w,fmaxf(xv.w,0.f), a))));
      }
      pxd_sh[tk][r] = a;
    }
  }

  const int dcnd = data_c[0];
  if (tid < 8)    tc_sh[tid]   = cond_emb[target_c[0]*8 + tid];
  if (tid < NTOK) outb_sh[tid] = outb[tid];
  h_sh[tid] = (tid >= HIDDEN-8) ? cond_emb[dcnd*8 + (tid-(HIDDEN-8))] : 0.f;
  if (tid < HPW){
    int idx = w*HPW + tid;
    c_sh[tid] = (idx >= HIDDEN-8) ? cond_emb[dcnd*8 + (idx-(HIDDEN-8))] : 0.f;
  }
  __syncthreads();

  int step = 1;
  // ---------------- encoder: 16 sequential steps ----------------
  for (int es=0; es<ENC_T; ++es, ++step){
    const float4* h4 = (const float4*)h_sh;
    float a = 0.f;
    #pragma unroll
    for (int k=0;k<8;++k){
      float4 hv = h4[p*8+k]; float4 wv = wenc[k];
      a = fmaf(wv.x,hv.x, fmaf(wv.y,hv.y, fmaf(wv.z,hv.z, fmaf(wv.w,hv.w, a))));
    }
    a += __shfl_xor(a,1); a += __shfl_xor(a,2); a += __shfl_xor(a,4);
    if (p==0) g_sh[r] = a + pxe_sh[es][r];
    __syncthreads();
    if (tid < HPW){
      float gi=g_sh[tid], gf=g_sh[8+tid], gg=g_sh[16+tid], go=g_sh[24+tid];
      float cc = sigf(gf)*c_sh[tid] + sigf(gi)*tanhf(gg);
      float hh = sigf(go)*tanhf(cc);
      c_sh[tid]=cc;
      const int idx = (step&1)*HIDDEN + w*HPW + tid;
      const u64 pkt = ((u64)(unsigned)step<<32) | (u64)__float_as_uint(hh);
      st_sc0(&hbL2[idx], pkt);
      astore(&hbIC[idx], pkt);
      if (es==ENC_T-1){
        const u64 cp = ((u64)(unsigned)step<<32) | (u64)__float_as_uint(cc);
        st_sc0(&cbL2[w*HPW + tid], cp);
        astore(&cbIC[w*HPW + tid], cp);
      }
    }
    // dual-path tagged poll, parity double-buffered
    {
      const int idx = (step&1)*HIDDEN + tid;
      h_sh[tid] = poll_dual(&hbL2[idx], &hbIC[idx], (unsigned)step);
    }
    __syncthreads();
  }

  // ---------------- mid: mu's + fc1/fc2 (redundant per WG, R4-identical) ----------------
  c2_sh[tid] = poll_dual(&cbL2[tid], &cbIC[tid], (unsigned)ENC_T);
  __syncthreads();
  {
    int row = tid>>2, q = tid&3;   // 64 rows (32 h_mu + 32 c_mu), 4 threads each
    const float* Wr = (row<32) ? (hmuW + (size_t)row*HIDDEN) : (cmuW + (size_t)(row-32)*HIDDEN);
    const float* v  = (row<32) ? h_sh : c2_sh;
    float a=0.f;
    for (int c4=q*16; c4<q*16+16; ++c4){
      float4 wv = ld4(Wr + c4*4);
      float4 vv = *(const float4*)(v + c4*4);
      a = fmaf(wv.x,vv.x, fmaf(wv.y,vv.y, fmaf(wv.z,vv.z, fmaf(wv.w,vv.w, a))));
    }
    a += __shfl_xor(a,1); a += __shfl_xor(a,2);
    if (q==0) mu_sh[row] = a + ((row<32)? hmub[row] : cmub[row-32]);
  }
  __syncthreads();
  {
    float a = fc1b[tid];
    const float* Wr = fc1W + (size_t)tid*40;
    #pragma unroll
    for (int k=0;k<32;++k) a = fmaf(Wr[k], mu_sh[k], a);
    #pragma unroll
    for (int k=0;k<8;++k)  a = fmaf(Wr[32+k], tc_sh[k], a);
    float a2 = 0.f;
    if (tid < HPW){
      int idx = w*HPW + tid;
      a2 = fc2b[idx];
      const float* W2 = fc2W + (size_t)idx*40;
      #pragma unroll
      for (int k=0;k<32;++k) a2 = fmaf(W2[k], mu_sh[32+k], a2);
      #pragma unroll
      for (int k=0;k<8;++k)  a2 = fmaf(W2[32+k], tc_sh[k], a2);
    }
    __syncthreads();
    h_sh[tid] = a;                 // decoder h0 (full, redundant in every WG)
    if (tid < HPW) c_sh[tid] = a2; // decoder c0 (own slice only)
    __syncthreads();
  }

  // ---------------- decoder: 25 sequential steps ----------------
  int tok = 0; // SOS
  for (int dt=0; dt<DECLEN; ++dt, ++step){
    const float4* h4 = (const float4*)h_sh;
    float a=0.f;
    #pragma unroll
    for (int k=0;k<8;++k){
      float4 hv = h4[p*8+k]; float4 wv = wdec[k];
      a = fmaf(wv.x,hv.x, fmaf(wv.y,hv.y, fmaf(wv.z,hv.z, fmaf(wv.w,hv.w, a))));
    }
    a += __shfl_xor(a,1); a += __shfl_xor(a,2); a += __shfl_xor(a,4);
    if (p==0) g_sh[r] = a + pxd_sh[tok][r];
    __syncthreads();
    if (tid < HPW){
      float gi=g_sh[tid], gf=g_sh[8+tid], gg=g_sh[16+tid], go=g_sh[24+tid];
      float cc = sigf(gf)*c_sh[tid] + sigf(gi)*tanhf(gg);
      float hh = sigf(go)*tanhf(cc);
      c_sh[tid]=cc;
      const int idx = (step&1)*HIDDEN + w*HPW + tid;
      const u64 pkt = ((u64)(unsigned)step<<32) | (u64)__float_as_uint(hh);
      st_sc0(&hbL2[idx], pkt);
      astore(&hbIC[idx], pkt);
    }
    {
      const int idx = (step&1)*HIDDEN + tid;
      h_sh[tid] = poll_dual(&hbL2[idx], &hbIC[idx], (unsigned)step);
    }
    __syncthreads();
    // logits + argmax, redundant in every WG (R4-identical order)
    {
      const float4* h4b = (const float4*)h_sh;
      if (r < NTOK){
        float la=0.f;
        #pragma unroll
        for (int k=0;k<8;++k){
          float4 hv = h4b[p*8+k]; float4 wv = wout[k];
          la = fmaf(wv.x,hv.x, fmaf(wv.y,hv.y, fmaf(wv.z,hv.z, fmaf(wv.w,hv.w, la))));
        }
        la += __shfl_xor(la,1); la += __shfl_xor(la,2); la += __shfl_xor(la,4);
        if (p==0) l_sh[r] = la + outb_sh[r];
      }
    }
    __syncthreads();
    if (tid==0){
      float best = l_sh[0]; int bi=0;
      #pragma unroll
      for (int i=1;i<NTOK;++i){ if (l_sh[i] > best){ best=l_sh[i]; bi=i; } }
      tok_sh = bi;
    }
    __syncthreads();
    tok = tok_sh;
    if (rep==0 && w==0){
      if (tid < NTOK) out[dt*NTOK + tid] = l_sh[tid];
      if (tid==0)     out[DECLEN*NTOK + dt] = (float)tok_sh;
    }
  }
}

extern "C" void kernel_launch(void* const* d_in, const int* in_sizes, int n_in,
                              void* d_out, int out_size, void* d_ws, size_t ws_size,
                              hipStream_t stream)
{
  int nrep = (ws_size >= (size_t)8 * REPSTRIDE * 8) ? 8 : 1;   // 8 replicas need 128 KB
  hipMemsetAsync(d_ws, 0, (size_t)nrep * REPSTRIDE * 8, stream);

  vae_lstm_kernel<<<32*nrep, NTHR, 0, stream>>>(
    (const int*)d_in[0], (const int*)d_in[1], (const int*)d_in[2],
    (const float*)d_in[3], (const float*)d_in[4],
    (const float*)d_in[5], (const float*)d_in[6], (const float*)d_in[7], (const float*)d_in[8],
    (const float*)d_in[9], (const float*)d_in[10], (const float*)d_in[11], (const float*)d_in[12],
    (const float*)d_in[13], (const float*)d_in[14], (const float*)d_in[15], (const float*)d_in[16],
    (const float*)d_in[17], (const float*)d_in[18], (const float*)d_in[19], (const float*)d_in[20],
    (const float*)d_in[21], (const float*)d_in[22], (const float*)d_in[23],
    (float*)d_out, (u64*)d_ws, nrep);
}